// Round 21
// baseline (39.121 us; speedup 1.0000x reference)
//
#include <hip/hip_runtime.h>

#define EPS_BN 1e-5f

typedef __attribute__((ext_vector_type(8))) short short8v;
typedef __attribute__((ext_vector_type(4))) float f32x4;
typedef __attribute__((ext_vector_type(4))) _Float16 h16x4;

__device__ inline unsigned short f2bf(float f) {
    union { float f; unsigned u; } v; v.f = f;
    unsigned r = v.u + 0x7fffu + ((v.u >> 16) & 1u);
    return (unsigned short)(r >> 16);
}

// ---------------------------------------------------------------------------
// Kernel A v5: 1x1 conv (256->64) MFMA + BN + SiLU -> tpad interior.
// A-tile staged ONCE per block into swizzled LDS bf16 [px16][ci256]
// (coalesced f4 global reads, b128 LDS fragment reads, XOR swizzle
// byte ^= (px&7)<<4 -> 2-way alias only).  Kills the 4x redundant
// stride-2304 scalar X reads.  Side jobs unchanged.
// grid (wseg=3, h=48, b=2), block 256.
// ---------------------------------------------------------------------------
__global__ __launch_bounds__(256) void comp_mfma(
    const float* __restrict__ X, const float* __restrict__ w_comp,
    const float* __restrict__ w_enc,
    const float* __restrict__ g1, const float* __restrict__ b1,
    const float* __restrict__ m1, const float* __restrict__ v1,
    unsigned short* __restrict__ tpad, unsigned short* __restrict__ Web)
{
    const int wseg = blockIdx.x;
    const int h = blockIdx.y;
    const int b = blockIdx.z;
    const int tid  = threadIdx.x;
    const int w0   = wseg * 16;

    __shared__ unsigned short xs[16 * 256];   // swizzled [px][ci] bf16, 8 KB

    // ---- side job 1: Web[ch][kk*64+ci] bf16 from w_enc[ch][ci][kk]
    {
        const int i = ((wseg + 3*(h + 48*b)) << 8) | tid;   // 0..73727
        const int ch = i / 576;
        const int r  = i - ch * 576;
        const int kk = r >> 6;
        const int ci = r & 63;
        const float v = (ch < 100) ? w_enc[ch * 576 + ci * 9 + kk] : 0.f;
        Web[i] = f2bf(v);
        // ---- side job 2: zero tpad border (196 px * 64 ch * 2 b)
        if (i < 25088) {
            const int bb  = i / 12544;
            const int rem = i - bb * 12544;
            const int p   = rem >> 6;
            const int chn = rem & 63;
            int rr, cc;
            if (p < 50)       { rr = 0;       cc = p;       }
            else if (p < 100) { rr = 49;      cc = p - 50;  }
            else if (p < 148) { rr = p - 99;  cc = 0;       }
            else              { rr = p - 147; cc = 49;      }
            tpad[((bb*50 + rr)*50 + cc)*64 + chn] = 0;
        }
    }

    // ---- stage A-tile: 256 ci x 16 px, coalesced f4 (4 lanes per 64B line)
    for (int idx = tid; idx < 1024; idx += 256) {
        const int ci = idx >> 2;
        const int q  = idx & 3;
        const float4 v = *(const float4*)&X[(size_t)(b*256 + ci)*2304 + h*48 + w0 + q*4];
        #pragma unroll
        for (int j = 0; j < 4; ++j) {
            const int px = q*4 + j;
            const int byte = (px*512 + ci*2) ^ ((px & 7) << 4);
            const float val = (j==0)?v.x:(j==1)?v.y:(j==2)?v.z:v.w;
            *(unsigned short*)((char*)xs + byte) = f2bf(val);
        }
    }
    __syncthreads();

    // ---- comp MFMA: A from LDS (b128), B cast on the fly from fp32 w_comp
    const int wave = tid >> 6;
    const int l    = tid & 63;
    const int lr   = l & 15;
    const int lk   = l >> 4;
    const float* wb = w_comp + (wave * 16 + lr) * 256;

    f32x4 acc = {0.f,0.f,0.f,0.f};
    #pragma unroll
    for (int s = 0; s < 8; ++s) {
        const int ci0 = s * 32 + lk * 8;
        const int byte = (lr*512 + ci0*2) ^ ((lr & 7) << 4);
        const short8v a = *(const short8v*)((char*)xs + byte);
        short8v f;
        const float4 wv0 = *(const float4*)(wb + ci0);
        const float4 wv1 = *(const float4*)(wb + ci0 + 4);
        f[0] = (short)f2bf(wv0.x); f[1] = (short)f2bf(wv0.y);
        f[2] = (short)f2bf(wv0.z); f[3] = (short)f2bf(wv0.w);
        f[4] = (short)f2bf(wv1.x); f[5] = (short)f2bf(wv1.y);
        f[6] = (short)f2bf(wv1.z); f[7] = (short)f2bf(wv1.w);
        acc = __builtin_amdgcn_mfma_f32_16x16x32_bf16(a, f, acc, 0, 0, 0);
    }

    const int oc = wave * 16 + lr;
    const float sc = g1[oc] * rsqrtf(v1[oc] + EPS_BN);
    const float sh = b1[oc] - m1[oc] * sc;
    unsigned short* tp = tpad + ((b*50 + h + 1)*50 + 1)*64 + oc;
    #pragma unroll
    for (int r = 0; r < 4; ++r) {
        float v = fmaf(acc[r], sc, sh);
        float t = v / (1.f + __expf(-v));          // SiLU
        tp[(w0 + lk*4 + r)*64] = f2bf(t);
    }
}

// ---------------------------------------------------------------------------
// Kernel B (R14/R16): 3x3 conv (64->100) MFMA + BN + fused softmax -> Wl fp16.
// grid (wseg=3, h=48, b=2), block 256 (4 waves).
// ---------------------------------------------------------------------------
__global__ __launch_bounds__(256) void enc_sm(
    const unsigned short* __restrict__ tpad, const unsigned short* __restrict__ Web,
    const float* __restrict__ g2, const float* __restrict__ b2,
    const float* __restrict__ m2, const float* __restrict__ v2,
    _Float16* __restrict__ Wl)
{
    const int wseg = blockIdx.x;
    const int h = blockIdx.y;
    const int b = blockIdx.z;
    const int tid  = threadIdx.x;
    const int wave = tid >> 6;
    const int l    = tid & 63;
    const int lr   = l & 15;
    const int lk   = l >> 4;
    const int w0   = wseg * 16;
    const int nt0  = wave * 2, nt1 = wave * 2 + 1;
    __shared__ float elds[16 * 116];

    f32x4 acc0 = {0.f,0.f,0.f,0.f};
    f32x4 acc1 = {0.f,0.f,0.f,0.f};

    const unsigned short* tb = tpad + (b*50 + h)*50*64;
    const unsigned short* wb0 = Web + (nt0*16 + lr)*576;
    const unsigned short* wb1 = Web + (nt1*16 + lr)*576;

    #pragma unroll 6
    for (int s = 0; s < 18; ++s) {
        const int kk = s >> 1;
        const int ky = (kk * 11) >> 5;
        const int kx = kk - ky * 3;
        const int cio = ((s & 1) << 5) + lk * 8;
        const short8v a  = *(const short8v*)(tb + (ky*50 + w0 + kx + lr)*64 + cio);
        const short8v f0 = *(const short8v*)(wb0 + kk*64 + cio);
        const short8v f1 = *(const short8v*)(wb1 + kk*64 + cio);
        acc0 = __builtin_amdgcn_mfma_f32_16x16x32_bf16(a, f0, acc0, 0, 0, 0);
        acc1 = __builtin_amdgcn_mfma_f32_16x16x32_bf16(a, f1, acc1, 0, 0, 0);
    }

    #pragma unroll
    for (int t = 0; t < 2; ++t) {
        const int nt = t ? nt1 : nt0;
        if (nt >= 7) continue;
        const int ch = nt*16 + lr;
        float sc = 0.f, sh = 0.f;
        if (ch < 100) {
            sc = g2[ch] * rsqrtf(v2[ch] + EPS_BN);
            sh = b2[ch] - m2[ch]*sc;
        }
        const f32x4 acc = t ? acc1 : acc0;
        #pragma unroll
        for (int r = 0; r < 4; ++r)
            elds[(lk*4 + r)*116 + ch] = fmaf(acc[r], sc, sh);
    }
    __syncthreads();

    if (tid < 64) {
        const int px = tid >> 2;
        const int s  = tid & 3;
        const float* ep = &elds[px*116 + s];
        float ev[25];
        float mx = -1e30f;
        #pragma unroll
        for (int k = 0; k < 25; ++k) { ev[k] = ep[4*k]; mx = fmaxf(mx, ev[k]); }
        float sum = 0.f;
        #pragma unroll
        for (int k = 0; k < 25; ++k) { ev[k] = __expf(ev[k] - mx); sum += ev[k]; }
        const float rs = 1.f / sum;
        _Float16* wp = Wl + ((b*48 + h)*48 + w0 + px)*112 + s*28;
        #pragma unroll
        for (int k4 = 0; k4 < 6; ++k4) {
            h16x4 o = { (_Float16)(ev[k4*4+0]*rs), (_Float16)(ev[k4*4+1]*rs),
                        (_Float16)(ev[k4*4+2]*rs), (_Float16)(ev[k4*4+3]*rs) };
            *(h16x4*)(wp + k4*4) = o;
        }
        wp[24] = (_Float16)(ev[24]*rs);
    }
}

// ---------------------------------------------------------------------------
// Kernel C v10 (R14/R16): fp16 Wl direct from L2, XCD swizzle, 2 barriers,
// xl 16.9 KB + ol 12 KB.  Flat grid 1536.
// ---------------------------------------------------------------------------
__global__ __launch_bounds__(256) void carafe_v10(
    const float* __restrict__ X, const _Float16* __restrict__ Wl,
    float* __restrict__ out)
{
    const int bid  = blockIdx.x;
    const int slot = bid & 7;
    const int k    = bid >> 3;          // 0..191
    const int h    = slot + 8 * (k % 6);
    const int cg   = (k / 6) & 15;
    const int b    = k / 96;

    __shared__ float xl[4240];    // [(ci>>2):4][r:5][cp:53][ci&3]
    __shared__ float ol[3072];    // [ch:16][y:2][x:96]
    const int tid = threadIdx.x;

    for (int idx = tid; idx < 960; idx += 256) {
        const int ci  = idx / 60;
        const int rem = idx - ci * 60;
        const int r   = rem / 12;
        const int q   = rem - r * 12;
        const int hh  = h - 2 + r;
        float4 v = {0.f,0.f,0.f,0.f};
        if ((unsigned)hh < 48u)
            v = *(const float4*)&X[(size_t)(b*256 + cg*16 + ci)*2304 + hh*48 + q*4];
        float* base = &xl[(((ci>>2)*5 + r)*53 + 2 + q*4)*4 + (ci&3)];
        base[0]  = v.x;
        base[4]  = v.y;
        base[8]  = v.z;
        base[12] = v.w;
    }
    for (int idx = tid; idx < 320; idx += 256) {
        const int ci  = idx / 20;
        const int rem = idx - ci * 20;
        const int r   = rem / 4;
        const int e   = rem & 3;
        const int cp  = (e < 2) ? e : 48 + e;
        xl[(((ci>>2)*5 + r)*53 + cp)*4 + (ci&3)] = 0.f;
    }
    __syncthreads();

    const int c4g = tid & 3;
    const int w   = tid >> 2;    // 0..63, active < 48
    if (w < 48) {
        float4 xv[25];
        #pragma unroll
        for (int r = 0; r < 5; ++r)
            #pragma unroll
            for (int dx = 0; dx < 5; ++dx)
                xv[r*5 + dx] = *(const float4*)&xl[((c4g*5 + r)*53 + (w + dx))*4];
        const _Float16* wb = &Wl[(size_t)((b*48 + h)*48 + w)*112];   // L2-local
        #pragma unroll
        for (int s = 0; s < 4; ++s) {
            float ax=0.f, ay=0.f, az=0.f, aw=0.f;
            #pragma unroll
            for (int k4 = 0; k4 < 6; ++k4) {
                const h16x4 hv = *(const h16x4*)&wb[s*28 + k4*4];
                const float w0f = (float)hv[0], w1f = (float)hv[1];
                const float w2f = (float)hv[2], w3f = (float)hv[3];
                const float4 p0 = xv[k4*4+0], p1 = xv[k4*4+1], p2 = xv[k4*4+2], p3 = xv[k4*4+3];
                ax = fmaf(w0f,p0.x,fmaf(w1f,p1.x,fmaf(w2f,p2.x,fmaf(w3f,p3.x,ax))));
                ay = fmaf(w0f,p0.y,fmaf(w1f,p1.y,fmaf(w2f,p2.y,fmaf(w3f,p3.y,ay))));
                az = fmaf(w0f,p0.z,fmaf(w1f,p1.z,fmaf(w2f,p2.z,fmaf(w3f,p3.z,az))));
                aw = fmaf(w0f,p0.w,fmaf(w1f,p1.w,fmaf(w2f,p2.w,fmaf(w3f,p3.w,aw))));
            }
            const float wk = (float)wb[s*28 + 24];
            const float4 pl = xv[24];
            ax = fmaf(wk,pl.x,ax); ay = fmaf(wk,pl.y,ay);
            az = fmaf(wk,pl.z,az); aw = fmaf(wk,pl.w,aw);
            const int y = s >> 1;
            const int x = 2*w + (s & 1);
            ol[((c4g*4 + 0)*2 + y)*96 + x] = ax;
            ol[((c4g*4 + 1)*2 + y)*96 + x] = ay;
            ol[((c4g*4 + 2)*2 + y)*96 + x] = az;
            ol[((c4g*4 + 3)*2 + y)*96 + x] = aw;
        }
    }
    __syncthreads();

    #pragma unroll
    for (int p = 0; p < 3; ++p) {
        const int fi = p*256 + tid;
        const int ch = fi / 48;
        const int rem = fi - ch*48;
        const int y  = rem / 24;
        const int xq = rem - y*24;
        const float4 v = *(const float4*)&ol[fi*4];
        *(float4*)&out[((size_t)(b*256 + cg*16 + ch)*96 + 2*h + y)*96 + xq*4] = v;
    }
}

extern "C" void kernel_launch(void* const* d_in, const int* in_sizes, int n_in,
                              void* d_out, int out_size, void* d_ws, size_t ws_size,
                              hipStream_t stream)
{
    (void)in_sizes; (void)n_in; (void)out_size; (void)ws_size;
    const float* X      = (const float*)d_in[0];
    const float* w_comp = (const float*)d_in[1];
    const float* g1     = (const float*)d_in[2];
    const float* b1     = (const float*)d_in[3];
    const float* m1     = (const float*)d_in[4];
    const float* v1     = (const float*)d_in[5];
    const float* w_enc  = (const float*)d_in[6];
    const float* g2     = (const float*)d_in[7];
    const float* b2     = (const float*)d_in[8];
    const float* m2     = (const float*)d_in[9];
    const float* v2     = (const float*)d_in[10];
    float* out = (float*)d_out;

    char* ws = (char*)d_ws;
    unsigned short* tpad = (unsigned short*)(ws + 0);        // 640000 B
    unsigned short* Web  = (unsigned short*)(ws + 640000);   // 147456 B
    _Float16*       Wl   = (_Float16*)(ws + 787456);         // 1032192 B

    dim3 gA(3, 48, 2);
    comp_mfma<<<gA, 256, 0, stream>>>(X, w_comp, w_enc, g1, b1, m1, v1, tpad, Web);
    dim3 gB(3, 48, 2);
    enc_sm<<<gB, 256, 0, stream>>>(tpad, Web, g2, b2, m2, v2, Wl);
    carafe_v10<<<1536, 256, 0, stream>>>(X, Wl, out);
}

// Round 22
// 38.454 us; speedup vs baseline: 1.0173x; 1.0173x over previous
//
#include <hip/hip_runtime.h>

#define EPS_BN 1e-5f

typedef __attribute__((ext_vector_type(8))) short short8v;
typedef __attribute__((ext_vector_type(4))) float f32x4;
typedef __attribute__((ext_vector_type(4))) _Float16 h16x4;

__device__ inline unsigned short f2bf(float f) {
    union { float f; unsigned u; } v; v.f = f;
    unsigned r = v.u + 0x7fffu + ((v.u >> 16) & 1u);
    return (unsigned short)(r >> 16);
}

// ---------------------------------------------------------------------------
// Kernel A v4 (R16/R20, best measured): 1x1 conv (256->64) MFMA + BN + SiLU
// -> tpad interior.  Full 64-element X prefetch.  Side jobs: Web + border.
// grid (wseg=3, h=48, b=2), block 256.
// ---------------------------------------------------------------------------
__global__ __launch_bounds__(256) void comp_mfma(
    const float* __restrict__ X, const float* __restrict__ w_comp,
    const float* __restrict__ w_enc,
    const float* __restrict__ g1, const float* __restrict__ b1,
    const float* __restrict__ m1, const float* __restrict__ v1,
    unsigned short* __restrict__ tpad, unsigned short* __restrict__ Web)
{
    const int wseg = blockIdx.x;
    const int h = blockIdx.y;
    const int b = blockIdx.z;
    const int tid  = threadIdx.x;

    // ---- side job 1: Web[ch][kk*64+ci] bf16 from w_enc[ch][ci][kk]
    {
        const int i = ((wseg + 3*(h + 48*b)) << 8) | tid;   // 0..73727
        const int ch = i / 576;
        const int r  = i - ch * 576;
        const int kk = r >> 6;
        const int ci = r & 63;
        const float v = (ch < 100) ? w_enc[ch * 576 + ci * 9 + kk] : 0.f;
        Web[i] = f2bf(v);
        // ---- side job 2: zero tpad border (196 px * 64 ch * 2 b)
        if (i < 25088) {
            const int bb  = i / 12544;
            const int rem = i - bb * 12544;
            const int p   = rem >> 6;
            const int chn = rem & 63;
            int rr, cc;
            if (p < 50)       { rr = 0;       cc = p;       }
            else if (p < 100) { rr = 49;      cc = p - 50;  }
            else if (p < 148) { rr = p - 99;  cc = 0;       }
            else              { rr = p - 147; cc = 49;      }
            tpad[((bb*50 + rr)*50 + cc)*64 + chn] = 0;
        }
    }

    // ---- main: comp MFMA with full X prefetch
    const int wave = tid >> 6;
    const int l    = tid & 63;
    const int lr   = l & 15;
    const int lk   = l >> 4;
    const int w0   = wseg * 16;

    const float* xb = X + (size_t)b * 589824 + h * 48 + w0 + lr;
    const float* wb = w_comp + (wave * 16 + lr) * 256;

    float xpre[64];
    #pragma unroll
    for (int s = 0; s < 8; ++s)
        #pragma unroll
        for (int j = 0; j < 8; ++j)
            xpre[s*8 + j] = xb[(size_t)(s*32 + lk*8 + j) * 2304];

    f32x4 acc = {0.f,0.f,0.f,0.f};
    #pragma unroll
    for (int s = 0; s < 8; ++s) {
        const int ci0 = s * 32 + lk * 8;
        short8v a, f;
        const float4 wv0 = *(const float4*)(wb + ci0);
        const float4 wv1 = *(const float4*)(wb + ci0 + 4);
        f[0] = (short)f2bf(wv0.x); f[1] = (short)f2bf(wv0.y);
        f[2] = (short)f2bf(wv0.z); f[3] = (short)f2bf(wv0.w);
        f[4] = (short)f2bf(wv1.x); f[5] = (short)f2bf(wv1.y);
        f[6] = (short)f2bf(wv1.z); f[7] = (short)f2bf(wv1.w);
        #pragma unroll
        for (int j = 0; j < 8; ++j)
            a[j] = (short)f2bf(xpre[s*8 + j]);
        acc = __builtin_amdgcn_mfma_f32_16x16x32_bf16(a, f, acc, 0, 0, 0);
    }

    const int oc = wave * 16 + lr;
    const float sc = g1[oc] * rsqrtf(v1[oc] + EPS_BN);
    const float sh = b1[oc] - m1[oc] * sc;
    unsigned short* tp = tpad + ((b*50 + h + 1)*50 + 1)*64 + oc;
    #pragma unroll
    for (int r = 0; r < 4; ++r) {
        float v = fmaf(acc[r], sc, sh);
        float t = v / (1.f + __expf(-v));          // SiLU
        tp[(w0 + lk*4 + r)*64] = f2bf(t);
    }
}

// ---------------------------------------------------------------------------
// Kernel B (R14/R16): 3x3 conv (64->100) MFMA + BN + fused softmax -> Wl fp16.
// grid (wseg=3, h=48, b=2), block 256 (4 waves).
// ---------------------------------------------------------------------------
__global__ __launch_bounds__(256) void enc_sm(
    const unsigned short* __restrict__ tpad, const unsigned short* __restrict__ Web,
    const float* __restrict__ g2, const float* __restrict__ b2,
    const float* __restrict__ m2, const float* __restrict__ v2,
    _Float16* __restrict__ Wl)
{
    const int wseg = blockIdx.x;
    const int h = blockIdx.y;
    const int b = blockIdx.z;
    const int tid  = threadIdx.x;
    const int wave = tid >> 6;
    const int l    = tid & 63;
    const int lr   = l & 15;
    const int lk   = l >> 4;
    const int w0   = wseg * 16;
    const int nt0  = wave * 2, nt1 = wave * 2 + 1;
    __shared__ float elds[16 * 116];

    f32x4 acc0 = {0.f,0.f,0.f,0.f};
    f32x4 acc1 = {0.f,0.f,0.f,0.f};

    const unsigned short* tb = tpad + (b*50 + h)*50*64;
    const unsigned short* wb0 = Web + (nt0*16 + lr)*576;
    const unsigned short* wb1 = Web + (nt1*16 + lr)*576;

    #pragma unroll 6
    for (int s = 0; s < 18; ++s) {
        const int kk = s >> 1;
        const int ky = (kk * 11) >> 5;
        const int kx = kk - ky * 3;
        const int cio = ((s & 1) << 5) + lk * 8;
        const short8v a  = *(const short8v*)(tb + (ky*50 + w0 + kx + lr)*64 + cio);
        const short8v f0 = *(const short8v*)(wb0 + kk*64 + cio);
        const short8v f1 = *(const short8v*)(wb1 + kk*64 + cio);
        acc0 = __builtin_amdgcn_mfma_f32_16x16x32_bf16(a, f0, acc0, 0, 0, 0);
        acc1 = __builtin_amdgcn_mfma_f32_16x16x32_bf16(a, f1, acc1, 0, 0, 0);
    }

    #pragma unroll
    for (int t = 0; t < 2; ++t) {
        const int nt = t ? nt1 : nt0;
        if (nt >= 7) continue;
        const int ch = nt*16 + lr;
        float sc = 0.f, sh = 0.f;
        if (ch < 100) {
            sc = g2[ch] * rsqrtf(v2[ch] + EPS_BN);
            sh = b2[ch] - m2[ch]*sc;
        }
        const f32x4 acc = t ? acc1 : acc0;
        #pragma unroll
        for (int r = 0; r < 4; ++r)
            elds[(lk*4 + r)*116 + ch] = fmaf(acc[r], sc, sh);
    }
    __syncthreads();

    if (tid < 64) {
        const int px = tid >> 2;
        const int s  = tid & 3;
        const float* ep = &elds[px*116 + s];
        float ev[25];
        float mx = -1e30f;
        #pragma unroll
        for (int k = 0; k < 25; ++k) { ev[k] = ep[4*k]; mx = fmaxf(mx, ev[k]); }
        float sum = 0.f;
        #pragma unroll
        for (int k = 0; k < 25; ++k) { ev[k] = __expf(ev[k] - mx); sum += ev[k]; }
        const float rs = 1.f / sum;
        _Float16* wp = Wl + ((b*48 + h)*48 + w0 + px)*112 + s*28;
        #pragma unroll
        for (int k4 = 0; k4 < 6; ++k4) {
            h16x4 o = { (_Float16)(ev[k4*4+0]*rs), (_Float16)(ev[k4*4+1]*rs),
                        (_Float16)(ev[k4*4+2]*rs), (_Float16)(ev[k4*4+3]*rs) };
            *(h16x4*)(wp + k4*4) = o;
        }
        wp[24] = (_Float16)(ev[24]*rs);
    }
}

// ---------------------------------------------------------------------------
// Kernel C v10 (R14/R16): fp16 Wl direct from L2, XCD swizzle, 2 barriers,
// xl 16.9 KB + ol 12 KB.  Flat grid 1536.
// ---------------------------------------------------------------------------
__global__ __launch_bounds__(256) void carafe_v10(
    const float* __restrict__ X, const _Float16* __restrict__ Wl,
    float* __restrict__ out)
{
    const int bid  = blockIdx.x;
    const int slot = bid & 7;
    const int k    = bid >> 3;          // 0..191
    const int h    = slot + 8 * (k % 6);
    const int cg   = (k / 6) & 15;
    const int b    = k / 96;

    __shared__ float xl[4240];    // [(ci>>2):4][r:5][cp:53][ci&3]
    __shared__ float ol[3072];    // [ch:16][y:2][x:96]
    const int tid = threadIdx.x;

    for (int idx = tid; idx < 960; idx += 256) {
        const int ci  = idx / 60;
        const int rem = idx - ci * 60;
        const int r   = rem / 12;
        const int q   = rem - r * 12;
        const int hh  = h - 2 + r;
        float4 v = {0.f,0.f,0.f,0.f};
        if ((unsigned)hh < 48u)
            v = *(const float4*)&X[(size_t)(b*256 + cg*16 + ci)*2304 + hh*48 + q*4];
        float* base = &xl[(((ci>>2)*5 + r)*53 + 2 + q*4)*4 + (ci&3)];
        base[0]  = v.x;
        base[4]  = v.y;
        base[8]  = v.z;
        base[12] = v.w;
    }
    for (int idx = tid; idx < 320; idx += 256) {
        const int ci  = idx / 20;
        const int rem = idx - ci * 20;
        const int r   = rem / 4;
        const int e   = rem & 3;
        const int cp  = (e < 2) ? e : 48 + e;
        xl[(((ci>>2)*5 + r)*53 + cp)*4 + (ci&3)] = 0.f;
    }
    __syncthreads();

    const int c4g = tid & 3;
    const int w   = tid >> 2;    // 0..63, active < 48
    if (w < 48) {
        float4 xv[25];
        #pragma unroll
        for (int r = 0; r < 5; ++r)
            #pragma unroll
            for (int dx = 0; dx < 5; ++dx)
                xv[r*5 + dx] = *(const float4*)&xl[((c4g*5 + r)*53 + (w + dx))*4];
        const _Float16* wb = &Wl[(size_t)((b*48 + h)*48 + w)*112];   // L2-local
        #pragma unroll
        for (int s = 0; s < 4; ++s) {
            float ax=0.f, ay=0.f, az=0.f, aw=0.f;
            #pragma unroll
            for (int k4 = 0; k4 < 6; ++k4) {
                const h16x4 hv = *(const h16x4*)&wb[s*28 + k4*4];
                const float w0f = (float)hv[0], w1f = (float)hv[1];
                const float w2f = (float)hv[2], w3f = (float)hv[3];
                const float4 p0 = xv[k4*4+0], p1 = xv[k4*4+1], p2 = xv[k4*4+2], p3 = xv[k4*4+3];
                ax = fmaf(w0f,p0.x,fmaf(w1f,p1.x,fmaf(w2f,p2.x,fmaf(w3f,p3.x,ax))));
                ay = fmaf(w0f,p0.y,fmaf(w1f,p1.y,fmaf(w2f,p2.y,fmaf(w3f,p3.y,ay))));
                az = fmaf(w0f,p0.z,fmaf(w1f,p1.z,fmaf(w2f,p2.z,fmaf(w3f,p3.z,az))));
                aw = fmaf(w0f,p0.w,fmaf(w1f,p1.w,fmaf(w2f,p2.w,fmaf(w3f,p3.w,aw))));
            }
            const float wk = (float)wb[s*28 + 24];
            const float4 pl = xv[24];
            ax = fmaf(wk,pl.x,ax); ay = fmaf(wk,pl.y,ay);
            az = fmaf(wk,pl.z,az); aw = fmaf(wk,pl.w,aw);
            const int y = s >> 1;
            const int x = 2*w + (s & 1);
            ol[((c4g*4 + 0)*2 + y)*96 + x] = ax;
            ol[((c4g*4 + 1)*2 + y)*96 + x] = ay;
            ol[((c4g*4 + 2)*2 + y)*96 + x] = az;
            ol[((c4g*4 + 3)*2 + y)*96 + x] = aw;
        }
    }
    __syncthreads();

    #pragma unroll
    for (int p = 0; p < 3; ++p) {
        const int fi = p*256 + tid;
        const int ch = fi / 48;
        const int rem = fi - ch*48;
        const int y  = rem / 24;
        const int xq = rem - y*24;
        const float4 v = *(const float4*)&ol[fi*4];
        *(float4*)&out[((size_t)(b*256 + cg*16 + ch)*96 + 2*h + y)*96 + xq*4] = v;
    }
}

extern "C" void kernel_launch(void* const* d_in, const int* in_sizes, int n_in,
                              void* d_out, int out_size, void* d_ws, size_t ws_size,
                              hipStream_t stream)
{
    (void)in_sizes; (void)n_in; (void)out_size; (void)ws_size;
    const float* X      = (const float*)d_in[0];
    const float* w_comp = (const float*)d_in[1];
    const float* g1     = (const float*)d_in[2];
    const float* b1     = (const float*)d_in[3];
    const float* m1     = (const float*)d_in[4];
    const float* v1     = (const float*)d_in[5];
    const float* w_enc  = (const float*)d_in[6];
    const float* g2     = (const float*)d_in[7];
    const float* b2     = (const float*)d_in[8];
    const float* m2     = (const float*)d_in[9];
    const float* v2     = (const float*)d_in[10];
    float* out = (float*)d_out;

    char* ws = (char*)d_ws;
    unsigned short* tpad = (unsigned short*)(ws + 0);        // 640000 B
    unsigned short* Web  = (unsigned short*)(ws + 640000);   // 147456 B
    _Float16*       Wl   = (_Float16*)(ws + 787456);         // 1032192 B

    dim3 gA(3, 48, 2);
    comp_mfma<<<gA, 256, 0, stream>>>(X, w_comp, w_enc, g1, b1, m1, v1, tpad, Web);
    dim3 gB(3, 48, 2);
    enc_sm<<<gB, 256, 0, stream>>>(tpad, Web, g2, b2, m2, v2, Wl);
    carafe_v10<<<1536, 256, 0, stream>>>(X, Wl, out);
}